// Round 1
// baseline (149.228 us; speedup 1.0000x reference)
//
#include <hip/hip_runtime.h>

#define B_ 4
#define C_ 256
#define H_ 128
#define W_ 128
#define Q_ 100
#define OH_ 7

// ---------------------------------------------------------------------------
// Kernel 1: row cumsum (along x) fused with NCHW -> NHWC transpose.
// Block = (b, y, cb) where cb selects 64 channels. 256 threads, 4 waves.
// LDS tile [64][129] (pad +1 -> stride 129 words, (c*129+x)%32 = (c+x)%32
// -> at most 2 lanes/bank, which is free on CDNA4).
// ---------------------------------------------------------------------------
__global__ __launch_bounds__(256) void rowscan_kernel(const float* __restrict__ x,
                                                      float* __restrict__ P) {
    __shared__ float tile[64][129];
    const int blk = blockIdx.x;            // b*512 + y*4 + cb
    const int cb  = blk & 3;
    const int y   = (blk >> 2) & 127;
    const int b   = blk >> 9;
    const int c0  = cb * 64;
    const int tid = threadIdx.x;

    const float* src = x + (((size_t)(b * C_ + c0) * H_ + y) * W_);
    // Load 64 rows x 128 floats. Lanes read consecutive x -> coalesced.
    #pragma unroll
    for (int i = 0; i < 32; ++i) {
        int l  = i * 256 + tid;
        int cl = l >> 7;        // 0..63
        int xx = l & 127;
        tile[cl][xx] = src[(size_t)cl * (H_ * W_) + xx];
    }
    __syncthreads();

    // Wave-parallel inclusive scan of each 128-wide row (2 elems/lane).
    const int wave = tid >> 6, lane = tid & 63;
    for (int r = wave; r < 64; r += 4) {
        float v0 = tile[r][2 * lane];
        float v1 = tile[r][2 * lane + 1];
        float s  = v0 + v1;                   // pair sum
        #pragma unroll
        for (int d = 1; d < 64; d <<= 1) {
            float t = __shfl_up(s, d);
            if (lane >= d) s += t;
        }
        float excl = s - (v0 + v1);           // exclusive prefix of pairs
        tile[r][2 * lane]     = excl + v0;
        tile[r][2 * lane + 1] = s;            // excl + v0 + v1
    }
    __syncthreads();

    // Write NHWC: P[((b*H + y)*W + x)*C + c]. Lanes write consecutive c
    // -> fully coalesced 256B/wave stores.
    float* dst = P + ((size_t)(b * H_ + y) * W_) * C_;
    #pragma unroll
    for (int i = 0; i < 32; ++i) {
        int l  = i * 256 + tid;
        int cl = l & 63;        // channel-local
        int xx = l >> 6;        // 0..127
        dst[(size_t)xx * C_ + (c0 + cl)] = tile[cl][xx];
    }
}

// ---------------------------------------------------------------------------
// Kernel 2: in-place column cumsum (along y) on the NHWC buffer.
// Thread per (b, x, c). Lanes = consecutive c -> coalesced.
// Unroll 8 so 8 loads are in flight per thread (latency hiding at the
// modest occupancy of 512 blocks).
// ---------------------------------------------------------------------------
__global__ __launch_bounds__(256) void colscan_kernel(float* __restrict__ P) {
    const int blk = blockIdx.x;            // b*W + x
    const int x   = blk & 127;
    const int b   = blk >> 7;
    const int c   = threadIdx.x;

    float* p = P + ((size_t)(b * H_ * W_) + x) * C_ + c;
    const size_t stride = (size_t)W_ * C_;

    float acc = 0.f;
    for (int y = 0; y < H_; y += 8) {
        float v[8];
        #pragma unroll
        for (int j = 0; j < 8; ++j) v[j] = p[(size_t)(y + j) * stride];
        #pragma unroll
        for (int j = 0; j < 8; ++j) {
            acc += v[j];
            p[(size_t)(y + j) * stride] = acc;
        }
    }
}

// ---------------------------------------------------------------------------
// Kernel 3: RoI gather. Block per (b,q), 512 threads (2 bins in flight,
// c = tid & 255). SAT is unpadded; padded coord (yy,xx) maps to
// (yy>0 && xx>0) ? S[yy-1][xx-1][c] : 0   (branch is wave-uniform per bin).
// Results staged in LDS, then written with linear coalesced stores to match
// the (B, Q*C, 7, 7) output layout.
// ---------------------------------------------------------------------------
__global__ __launch_bounds__(512) void gather_kernel(const float* __restrict__ S,
                                                     const int* __restrict__ rois,
                                                     float* __restrict__ out) {
    __shared__ float obuf[C_ * 49];
    __shared__ int   eg[28];   // ys[7], ye[7], xs[7], xe[7]

    const int bq  = blockIdx.x;       // b*Q + q
    const int b   = bq / Q_;
    const int tid = threadIdx.x;

    const int* r = rois + (size_t)bq * 5;
    if (tid < 28) {
        int x1 = r[1], y1 = r[2], x2 = r[3], y2 = r[4];
        int Lx = x2 - x1, Ly = y2 - y1;
        int g = tid / 7, k = tid % 7;
        int v;
        if (g == 0)      v = y1 + (k * Ly) / 7;              // ys: floor
        else if (g == 1) v = y1 + ((k + 1) * Ly + 6) / 7;    // ye: ceil
        else if (g == 2) v = x1 + (k * Lx) / 7;              // xs: floor
        else             v = x1 + ((k + 1) * Lx + 6) / 7;    // xe: ceil
        eg[tid] = v;
    }
    __syncthreads();

    const float* Sb   = S + (size_t)b * (H_ * W_ * C_);
    const int    c    = tid & 255;
    const int    half = tid >> 8;

    for (int bin0 = 0; bin0 < 49; bin0 += 2) {
        int bin = bin0 + half;
        if (bin < 49) {
            int oy = bin / 7, ox = bin % 7;
            int ys = eg[oy], ye = eg[7 + oy];
            int xs = eg[14 + ox], xe = eg[21 + ox];
            // ye >= 1 and xe >= 1 always (lengths >= 8)
            float s11 = Sb[((size_t)(ye - 1) * W_ + (xe - 1)) * C_ + c];
            float s01 = (ys > 0) ? Sb[((size_t)(ys - 1) * W_ + (xe - 1)) * C_ + c] : 0.f;
            float s10 = (xs > 0) ? Sb[((size_t)(ye - 1) * W_ + (xs - 1)) * C_ + c] : 0.f;
            float s00 = (ys > 0 && xs > 0)
                          ? Sb[((size_t)(ys - 1) * W_ + (xs - 1)) * C_ + c] : 0.f;
            float area = (float)((ye - ys) * (xe - xs));
            obuf[c * 49 + bin] = (s11 - s01 - s10 + s00) / area;
        }
    }
    __syncthreads();

    // Output layout: ((b*Q + q)*C + c)*49 + oy*7 + ox  -> obuf is exactly
    // that ordering for this (b,q); linear coalesced copy.
    float* ob = out + (size_t)bq * (C_ * 49);
    for (int i = tid; i < C_ * 49; i += 512) ob[i] = obuf[i];
}

extern "C" void kernel_launch(void* const* d_in, const int* in_sizes, int n_in,
                              void* d_out, int out_size, void* d_ws, size_t ws_size,
                              hipStream_t stream) {
    const float* x    = (const float*)d_in[0];
    const int*   rois = (const int*)d_in[1];
    float*       outp = (float*)d_out;
    float*       P    = (float*)d_ws;   // 4*128*128*256*4 = 64 MiB NHWC SAT

    rowscan_kernel<<<B_ * H_ * 4, 256, 0, stream>>>(x, P);
    colscan_kernel<<<B_ * W_, 256, 0, stream>>>(P);
    gather_kernel<<<B_ * Q_, 512, 0, stream>>>(P, rois, outp);
}